// Round 7
// baseline (4887.634 us; speedup 1.0000x reference)
//
#include <hip/hip_runtime.h>
#include <cstdint>
#include <cstddef>

typedef _Float16 f16;
typedef _Float16 f16x4 __attribute__((ext_vector_type(4)));
typedef _Float16 f16x8 __attribute__((ext_vector_type(8)));
typedef float f32x4 __attribute__((ext_vector_type(4)));

#define MFMA16(a, b, c) __builtin_amdgcn_mfma_f32_16x16x16f16((a), (b), (c), 0, 0, 0)
#define MFMA32(a, b, c) __builtin_amdgcn_mfma_f32_16x16x32_f16((a), (b), (c), 0, 0, 0)

constexpr int TT = 1024, DIN = 128, DH = 512, DOUT = 128;
constexpr size_t O_ELEMS = (size_t)64 * 1024 * 128;

// ---------------- Pass 1: xI = X(65536x128) @ wI(128x512) -> H region (fp32) ----------------
__global__ __launch_bounds__(256, 1) void k_xI(const float* __restrict__ X,
                                               const float* __restrict__ wI,
                                               float* __restrict__ xI) {
    __shared__ __align__(16) f16 Bt[DH][136];
    __shared__ __align__(16) f16 At[64][136];
    const int tid = threadIdx.x;
    const int wv = tid >> 6, ln = tid & 63, l15 = ln & 15, g = ln >> 4;
    const int m0 = (int)blockIdx.x * 64;

    for (int u = 0; u < 64; ++u) {
        int flat = u * 256 + tid;
        int r = flat >> 7;
        int c4 = (flat & 127) << 2;
        const float4 w4 = *(const float4*)(wI + (size_t)r * DH + c4);
        Bt[c4 + 0][r] = (f16)w4.x;
        Bt[c4 + 1][r] = (f16)w4.y;
        Bt[c4 + 2][r] = (f16)w4.z;
        Bt[c4 + 3][r] = (f16)w4.w;
    }
    {
        int r = tid >> 2;
        int cb = (tid & 3) << 5;
        #pragma unroll
        for (int u = 0; u < 8; ++u) {
            int c = cb + u * 4;
            const float4 x4 = *(const float4*)(X + (size_t)(m0 + r) * DIN + c);
            f16x4 h4;
            h4[0] = (f16)x4.x; h4[1] = (f16)x4.y; h4[2] = (f16)x4.z; h4[3] = (f16)x4.w;
            *(f16x4*)((char*)&At[r][0] + c * 2) = h4;
        }
    }
    __syncthreads();

    f32x4 acc[4][8];
    #pragma unroll
    for (int mt = 0; mt < 4; ++mt)
        #pragma unroll
        for (int nt = 0; nt < 8; ++nt) acc[mt][nt] = (f32x4){0.f, 0.f, 0.f, 0.f};

    #pragma unroll
    for (int c = 0; c < 8; ++c) {
        const int k0 = c * 16 + g * 4;
        f16x4 a[4];
        #pragma unroll
        for (int mt = 0; mt < 4; ++mt)
            a[mt] = *(const f16x4*)((const char*)&At[mt * 16 + l15][0] + k0 * 2);
        #pragma unroll
        for (int nt = 0; nt < 8; ++nt) {
            const int n = wv * 128 + nt * 16 + l15;
            const f16x4 b = *(const f16x4*)((const char*)&Bt[n][0] + k0 * 2);
            #pragma unroll
            for (int mt = 0; mt < 4; ++mt) acc[mt][nt] = MFMA16(a[mt], b, acc[mt][nt]);
        }
    }
    #pragma unroll
    for (int mt = 0; mt < 4; ++mt) {
        #pragma unroll
        for (int i = 0; i < 4; ++i) {
            const int m = m0 + mt * 16 + g * 4 + i;
            float* orow = xI + (size_t)m * DH + wv * 128 + l15;
            #pragma unroll
            for (int nt = 0; nt < 8; ++nt) orow[nt * 16] = acc[mt][nt][i];
        }
    }
}

// ---------------- Pass 2: recurrent scan -------------------------------------------------
// 4 blocks x 16 batches, 4 waves/block (1/SIMD, 512-reg unified budget).
// Per wave: 128 j = 8 tiles: 6 in registers (f16x8 Brf[6][16] = 384 regs; used only
// as MFMA B-operands so the AV register class can hold them in AGPRs with direct
// MFMA reads), 2 in LDS. All-intrinsic MFMA (compiler-managed hazards).
// LDS (163840 B exactly):
//   [0,16K)    hb[0]: h, [16 r][512 k] f16, swizzled  |  [16K,32K) hb[1]
//   [32K,160K) 8 B j-tiles (2/wave), [16 j][512 k] f16, swizzled
// Swizzle: addr = row*1024 + (byteoff ^ ((row&7)<<4)).
__global__ __launch_bounds__(256, 1) void k_scan(const float* __restrict__ wR,
                                                 const float* __restrict__ h0,
                                                 float* __restrict__ Hb) {
    __shared__ __align__(16) char sm[163840];
    const int tid = threadIdx.x;
    const int wv = tid >> 6, ln = tid & 63, l15 = ln & 15, g = ln >> 4;
    const int bb = (int)blockIdx.x * 16;

    // ---- stage wR: 6 register j-tiles per wave (j = wv*128 + q*16 + l15) ----
    f16x8 Brf[6][16];
    #pragma unroll
    for (int q = 0; q < 6; ++q) {
        const int j = wv * 128 + q * 16 + l15;
        #pragma unroll
        for (int c = 0; c < 16; ++c) {
            const float* pw = wR + (size_t)(c * 32 + g * 8) * DH + j;
            f16x8 v;
            #pragma unroll
            for (int i = 0; i < 8; ++i) v[i] = (f16)pw[(size_t)i * DH];
            Brf[q][c] = v;
        }
    }
    // ---- stage wR: 2 LDS j-tiles per wave (tile T=wv*2+s: j = wv*128+96+s*16+jj) ----
    for (int idx = tid; idx < 8 * 16 * 512; idx += 256) {
        const int jj = idx & 15;
        const int k = (idx >> 4) & 511;
        const int T = idx >> 13;
        const float v = wR[(size_t)k * DH + (T >> 1) * 128 + 96 + (T & 1) * 16 + jj];
        *(f16*)(sm + 32768 + T * 16384 + jj * 1024 +
                (((uint32_t)(k * 2)) ^ (((uint32_t)(jj & 7)) << 4))) = (f16)v;
    }
    // ---- h0 broadcast into hb[0] ----
    #pragma unroll
    for (int u = 0; u < 2; ++u) {
        const int j = tid + u * 256;
        const f16 v = (f16)h0[j];
        #pragma unroll
        for (uint32_t r = 0; r < 16; ++r)
            *(f16*)(sm + r * 1024 + (((uint32_t)(j * 2)) ^ ((r & 7u) << 4))) = v;
    }

    const int jbase = wv * 128 + l15;
    float* Hp[4];
    #pragma unroll
    for (int i = 0; i < 4; ++i)
        Hp[i] = Hb + (size_t)(bb + g * 4 + i) * TT * DH + jbase;

    const uint32_t pre = ((uint32_t)(g ^ (l15 & 7))) << 4;  // k-chunk offset: (c<<6)^pre
    const char* hb_l0 = sm + (uint32_t)l15 * 1024;
    const char* hb_l1 = hb_l0 + 16384;
    const char* b6p = sm + 32768 + (uint32_t)(wv * 2) * 16384 + (uint32_t)l15 * 1024;
    const char* b7p = b6p + 16384;
    const uint32_t jb2 = (uint32_t)jbase * 2;

    // prologue: xI(0) into xr
    float xr[8][4];
    #pragma unroll
    for (int q = 0; q < 8; ++q)
        #pragma unroll
        for (int i = 0; i < 4; ++i) xr[q][i] = Hp[i][q * 16];

    f32x4 acc[8];

    __syncthreads();

    #pragma unroll 1
    for (int t = 0; t < TT; ++t) {
        const uint32_t p = (uint32_t)(t & 1);
        // deferred H stores of step t-1 (Hp points at row t; acc holds th(t-1))
        if (t > 0) {
            #pragma unroll
            for (int q = 0; q < 8; ++q)
                #pragma unroll
                for (int i = 0; i < 4; ++i) Hp[i][q * 16 - 512] = acc[q][i];
        }
        // acc <- xI(t) (MFMA C-in), then reuse xr for the t+1 prefetch
        #pragma unroll
        for (int q = 0; q < 8; ++q)
            #pragma unroll
            for (int i = 0; i < 4; ++i) acc[q][i] = xr[q][i];
        if (t + 1 < TT) {
            #pragma unroll
            for (int q = 0; q < 8; ++q)
                #pragma unroll
                for (int i = 0; i < 4; ++i) xr[q][i] = Hp[i][q * 16 + 512];
        }

        // h @ wR : 16 K=32 chunks; 6 register + 2 LDS B-tiles; A 1-deep prefetch
        {
            const char* hbp = p ? hb_l1 : hb_l0;
            f16x8 a0 = *(const f16x8*)(hbp + (0u ^ pre));
            #pragma unroll
            for (int c = 0; c < 16; ++c) {
                const uint32_t off = (((uint32_t)c) << 6) ^ pre;
                const f16x8 b6 = *(const f16x8*)(b6p + off);
                const f16x8 b7 = *(const f16x8*)(b7p + off);
                f16x8 a1;
                if (c < 15) a1 = *(const f16x8*)(hbp + ((((uint32_t)c + 1) << 6) ^ pre));
                acc[0] = MFMA32(a0, Brf[0][c], acc[0]);
                acc[1] = MFMA32(a0, Brf[1][c], acc[1]);
                acc[2] = MFMA32(a0, Brf[2][c], acc[2]);
                acc[3] = MFMA32(a0, Brf[3][c], acc[3]);
                acc[4] = MFMA32(a0, Brf[4][c], acc[4]);
                acc[5] = MFMA32(a0, Brf[5][c], acc[5]);
                acc[6] = MFMA32(a0, b6, acc[6]);
                acc[7] = MFMA32(a0, b7, acc[7]);
                if (c < 15) a0 = a1;
            }
        }

        // epilogue: th = tanh(acc); acc keeps fp32 th; hb[p^1] <- f16 th
        {
            char* hw = sm + (p ^ 1u) * 16384;
            #pragma unroll
            for (int q = 0; q < 8; ++q) {
                #pragma unroll
                for (int i = 0; i < 4; ++i) {
                    const uint32_t r = (uint32_t)g * 4 + (uint32_t)i;
                    const float x = acc[q][i];
                    const float e = __builtin_amdgcn_exp2f(x * 2.8853900817779268f);
                    const float th = 1.0f - 2.0f * __builtin_amdgcn_rcpf(e + 1.0f);
                    acc[q][i] = th;
                    *(f16*)(hw + r * 1024 +
                            ((jb2 + (uint32_t)q * 32) ^ ((r & 7u) << 4))) = (f16)th;
                }
            }
        }
        __syncthreads();  // hb[p^1] complete before next step reads it

        #pragma unroll
        for (int i = 0; i < 4; ++i) Hp[i] += DH;
    }
    // final stores (Hp points at row TT)
    #pragma unroll
    for (int q = 0; q < 8; ++q)
        #pragma unroll
        for (int i = 0; i < 4; ++i) Hp[i][q * 16 - 512] = acc[q][i];
}

// ---------------- Pass 3: O = H(65536x512) @ wO(512x128) ----------------
__global__ __launch_bounds__(256, 1) void k_O(const float* __restrict__ H,
                                              const float* __restrict__ wO,
                                              float* __restrict__ O) {
    __shared__ __align__(16) f16 Bt[DOUT][520];
    __shared__ __align__(16) f16 At[64][136];
    const int tid = threadIdx.x;
    const int wv = tid >> 6, ln = tid & 63, l15 = ln & 15, g = ln >> 4;
    const int m0 = (int)blockIdx.x * 64;

    for (int u = 0; u < 64; ++u) {
        int flat = u * 256 + tid;
        int r = flat >> 5;
        int c4 = (flat & 31) << 2;
        const float4 w4 = *(const float4*)(wO + (size_t)r * DOUT + c4);
        Bt[c4 + 0][r] = (f16)w4.x;
        Bt[c4 + 1][r] = (f16)w4.y;
        Bt[c4 + 2][r] = (f16)w4.z;
        Bt[c4 + 3][r] = (f16)w4.w;
    }

    f32x4 acc[8];
    #pragma unroll
    for (int nt = 0; nt < 8; ++nt) acc[nt] = (f32x4){0.f, 0.f, 0.f, 0.f};

    for (int kc = 0; kc < 4; ++kc) {
        __syncthreads();
        {
            int r = tid >> 2;
            int cb = (tid & 3) << 5;
            #pragma unroll
            for (int u = 0; u < 8; ++u) {
                int c = cb + u * 4;
                const float4 x4 = *(const float4*)(H + (size_t)(m0 + r) * DH + kc * 128 + c);
                f16x4 h4;
                h4[0] = (f16)x4.x; h4[1] = (f16)x4.y; h4[2] = (f16)x4.z; h4[3] = (f16)x4.w;
                *(f16x4*)((char*)&At[r][0] + c * 2) = h4;
            }
        }
        __syncthreads();
        #pragma unroll
        for (int c = 0; c < 8; ++c) {
            const int k0 = c * 16 + g * 4;
            const f16x4 a = *(const f16x4*)((const char*)&At[wv * 16 + l15][0] + k0 * 2);
            #pragma unroll
            for (int nt = 0; nt < 8; ++nt) {
                const f16x4 b =
                    *(const f16x4*)((const char*)&Bt[nt * 16 + l15][0] + (kc * 128 + k0) * 2);
                acc[nt] = MFMA16(a, b, acc[nt]);
            }
        }
    }
    #pragma unroll
    for (int i = 0; i < 4; ++i) {
        const int m = m0 + wv * 16 + g * 4 + i;
        #pragma unroll
        for (int nt = 0; nt < 8; ++nt) O[(size_t)m * DOUT + nt * 16 + l15] = acc[nt][i];
    }
}

extern "C" void kernel_launch(void* const* d_in, const int* in_sizes, int n_in,
                              void* d_out, int out_size, void* d_ws, size_t ws_size,
                              hipStream_t stream) {
    const float* X  = (const float*)d_in[0];
    const float* h0 = (const float*)d_in[1];
    const float* wI = (const float*)d_in[2];
    const float* wR = (const float*)d_in[3];
    const float* wO = (const float*)d_in[4];
    float* O = (float*)d_out;
    float* H = O + O_ELEMS;  // H region; also holds xI (fp32) before in-place scan

    k_xI<<<1024, 256, 0, stream>>>(X, wI, H);   // xI -> H region
    k_scan<<<4, 256, 0, stream>>>(wR, h0, H);   // in-place: xI -> H
    k_O<<<1024, 256, 0, stream>>>(H, wO, O);    // O = H @ wO
}

// Round 8
// 4056.276 us; speedup vs baseline: 1.2050x; 1.2050x over previous
//
#include <hip/hip_runtime.h>
#include <cstdint>
#include <cstddef>

typedef _Float16 f16;
typedef _Float16 f16x4 __attribute__((ext_vector_type(4)));
typedef _Float16 f16x8 __attribute__((ext_vector_type(8)));
typedef float f32x4 __attribute__((ext_vector_type(4)));

#define MFMA16(a, b, c) __builtin_amdgcn_mfma_f32_16x16x16f16((a), (b), (c), 0, 0, 0)
#define MFMA32(a, b, c) __builtin_amdgcn_mfma_f32_16x16x32_f16((a), (b), (c), 0, 0, 0)

constexpr int TT = 1024, DIN = 128, DH = 512, DOUT = 128;
constexpr size_t O_ELEMS = (size_t)64 * 1024 * 128;

// Row swizzle for [row][1KB] LDS tiles. ((r&7)<<4) spreads 8 rows over granules;
// ((r&8)<<2) splits rows i / 8+i so the 4 rows of one epilogue-write instruction
// land in 4 distinct 16B granule-pairs (2 lanes/dword = conflict-free, m136).
// b128 operand reads stay uniform: slot = 4c ^ g ^ (l15&7) ^ 2*(l15>>3) -> 8 lanes
// per slot = the 8-cy wave64 floor.
__device__ __forceinline__ uint32_t SW(uint32_t r) {
    return ((r & 7u) << 4) ^ ((r & 8u) << 2);
}

// ---------------- Pass 1: xI = X(65536x128) @ wI(128x512) -> H region (fp32) ----------------
__global__ __launch_bounds__(256, 1) void k_xI(const float* __restrict__ X,
                                               const float* __restrict__ wI,
                                               float* __restrict__ xI) {
    __shared__ __align__(16) f16 Bt[DH][136];
    __shared__ __align__(16) f16 At[64][136];
    const int tid = threadIdx.x;
    const int wv = tid >> 6, ln = tid & 63, l15 = ln & 15, g = ln >> 4;
    const int m0 = (int)blockIdx.x * 64;

    for (int u = 0; u < 64; ++u) {
        int flat = u * 256 + tid;
        int r = flat >> 7;
        int c4 = (flat & 127) << 2;
        const float4 w4 = *(const float4*)(wI + (size_t)r * DH + c4);
        Bt[c4 + 0][r] = (f16)w4.x;
        Bt[c4 + 1][r] = (f16)w4.y;
        Bt[c4 + 2][r] = (f16)w4.z;
        Bt[c4 + 3][r] = (f16)w4.w;
    }
    {
        int r = tid >> 2;
        int cb = (tid & 3) << 5;
        #pragma unroll
        for (int u = 0; u < 8; ++u) {
            int c = cb + u * 4;
            const float4 x4 = *(const float4*)(X + (size_t)(m0 + r) * DIN + c);
            f16x4 h4;
            h4[0] = (f16)x4.x; h4[1] = (f16)x4.y; h4[2] = (f16)x4.z; h4[3] = (f16)x4.w;
            *(f16x4*)((char*)&At[r][0] + c * 2) = h4;
        }
    }
    __syncthreads();

    f32x4 acc[4][8];
    #pragma unroll
    for (int mt = 0; mt < 4; ++mt)
        #pragma unroll
        for (int nt = 0; nt < 8; ++nt) acc[mt][nt] = (f32x4){0.f, 0.f, 0.f, 0.f};

    #pragma unroll
    for (int c = 0; c < 8; ++c) {
        const int k0 = c * 16 + g * 4;
        f16x4 a[4];
        #pragma unroll
        for (int mt = 0; mt < 4; ++mt)
            a[mt] = *(const f16x4*)((const char*)&At[mt * 16 + l15][0] + k0 * 2);
        #pragma unroll
        for (int nt = 0; nt < 8; ++nt) {
            const int n = wv * 128 + nt * 16 + l15;
            const f16x4 b = *(const f16x4*)((const char*)&Bt[n][0] + k0 * 2);
            #pragma unroll
            for (int mt = 0; mt < 4; ++mt) acc[mt][nt] = MFMA16(a[mt], b, acc[mt][nt]);
        }
    }
    #pragma unroll
    for (int mt = 0; mt < 4; ++mt) {
        #pragma unroll
        for (int i = 0; i < 4; ++i) {
            const int m = m0 + mt * 16 + g * 4 + i;
            float* orow = xI + (size_t)m * DH + wv * 128 + l15;
            #pragma unroll
            for (int nt = 0; nt < 8; ++nt) orow[nt * 16] = acc[mt][nt][i];
        }
    }
}

// ---------------- Pass 2: recurrent scan -------------------------------------------------
// 4 blocks x 16 batches, 8 waves/block (2/SIMD). Full-rate x32 MFMA (K=32 chunks).
// Per wave: 64 j = 4 tiles; 3 in registers (f16x8 Brf[3][16]), 1 in LDS (forced:
// hb 32KB + 8x16KB B-tiles = 160KB exactly).
// Step barrier is a COUNTED barrier (lgkmcnt only): the in-flight xI prefetch
// loads / H stores cross it without a vmcnt(0) drain (the __syncthreads drain
// was ~30% of the step). Correctness needs only LDS visibility: hb is
// double-buffered, and lgkmcnt(0) covers both this wave's hb writes and reads.
__global__ __launch_bounds__(512, 2) void k_scan(const float* __restrict__ wR,
                                                 const float* __restrict__ h0,
                                                 float* __restrict__ Hb) {
    __shared__ __align__(16) char sm[163840];
    const int tid = threadIdx.x;
    const int wv = tid >> 6, ln = tid & 63, l15 = ln & 15, g = ln >> 4;
    const int bb = (int)blockIdx.x * 16;

    // ---- stage wR: 3 register j-tiles per wave; frag[i] = wR[c*32+g*8+i][j] ----
    f16x8 Brf[3][16];
    #pragma unroll
    for (int q = 0; q < 3; ++q) {
        const int j = wv * 64 + q * 16 + l15;
        #pragma unroll
        for (int c = 0; c < 16; ++c) {
            const float* pw = wR + (size_t)(c * 32 + g * 8) * DH + j;
            f16x8 v;
            #pragma unroll
            for (int i = 0; i < 8; ++i) v[i] = (f16)pw[(size_t)i * DH];
            Brf[q][c] = v;
        }
    }
    // ---- stage wR: 1 LDS j-tile per wave (j = t8*64 + 48 + j16), cooperative ----
    for (int idx = tid; idx < 8 * 16 * 512; idx += 512) {
        const int j16 = idx & 15;
        const int k = (idx >> 4) & 511;
        const int t8 = idx >> 13;
        const float v = wR[(size_t)k * DH + t8 * 64 + 48 + j16];
        *(f16*)(sm + 32768 + t8 * 16384 + j16 * 1024 +
                (((uint32_t)(k * 2)) ^ SW((uint32_t)j16))) = (f16)v;
    }
    // ---- h0 broadcast into hb[0] ----
    {
        const int j = tid;  // 0..511
        const f16 v = (f16)h0[j];
        #pragma unroll
        for (uint32_t r = 0; r < 16; ++r)
            *(f16*)(sm + r * 1024 + (((uint32_t)(j * 2)) ^ SW(r))) = v;
    }

    const int jbase = wv * 64 + l15;
    float* Hp[4];
    #pragma unroll
    for (int i = 0; i < 4; ++i)
        Hp[i] = Hb + (size_t)(bb + g * 4 + i) * TT * DH + jbase;

    // k-chunk offset: off = (c<<6) ^ pre
    const uint32_t pre =
        (((uint32_t)(g ^ (l15 & 7))) << 4) ^ (((uint32_t)(l15 & 8)) << 2);
    const uint32_t lanebase = (uint32_t)l15 * 1024;
    const uint32_t jb2 = (uint32_t)jbase * 2;

    // prologue: xI(0) into xr
    float xr[4][4];
    #pragma unroll
    for (int q = 0; q < 4; ++q)
        #pragma unroll
        for (int i = 0; i < 4; ++i) xr[q][i] = Hp[i][q * 16];

    f32x4 acc[4];

    __syncthreads();

    #pragma unroll 1
    for (int t = 0; t < TT; ++t) {
        const uint32_t p = (uint32_t)(t & 1);
        // deferred H stores of step t-1 (Hp points at row t)
        if (t > 0) {
            #pragma unroll
            for (int q = 0; q < 4; ++q)
                #pragma unroll
                for (int i = 0; i < 4; ++i) Hp[i][q * 16 - 512] = acc[q][i];
        }
        // acc <- xI(t)  (MFMA C-in carries the input projection)
        #pragma unroll
        for (int q = 0; q < 4; ++q)
            #pragma unroll
            for (int i = 0; i < 4; ++i) acc[q][i] = xr[q][i];
        // prefetch xI(t+1); loads stay in flight across the counted barrier
        if (t + 1 < TT) {
            #pragma unroll
            for (int q = 0; q < 4; ++q)
                #pragma unroll
                for (int i = 0; i < 4; ++i) xr[q][i] = Hp[i][q * 16 + 512];
        }

        // h @ wR : 16 K=32 chunks, 3 register B-tiles + 1 LDS B-tile
        {
            const char* hbp = sm + p * 16384 + lanebase;
            const char* blp = sm + 32768 + (uint32_t)wv * 16384 + lanebase;
            #pragma unroll
            for (int c = 0; c < 16; ++c) {
                const uint32_t off = (((uint32_t)c) << 6) ^ pre;
                const f16x8 a = *(const f16x8*)(hbp + off);
                acc[0] = MFMA32(a, Brf[0][c], acc[0]);
                acc[1] = MFMA32(a, Brf[1][c], acc[1]);
                acc[2] = MFMA32(a, Brf[2][c], acc[2]);
                const f16x8 b3 = *(const f16x8*)(blp + off);
                acc[3] = MFMA32(a, b3, acc[3]);
            }
        }

        // epilogue: th = tanh(acc); acc keeps fp32 th; hb[p^1] <- f16 th
        {
            char* hw = sm + (p ^ 1u) * 16384;
            #pragma unroll
            for (int q = 0; q < 4; ++q) {
                #pragma unroll
                for (int i = 0; i < 4; ++i) {
                    const uint32_t r = (uint32_t)g * 4 + (uint32_t)i;
                    const float x = acc[q][i];
                    const float e = __builtin_amdgcn_exp2f(x * 2.8853900817779268f);
                    const float th = 1.0f - 2.0f * __builtin_amdgcn_rcpf(e + 1.0f);
                    acc[q][i] = th;
                    *(f16*)(hw + r * 1024 + ((jb2 + (uint32_t)q * 32) ^ SW(r))) = (f16)th;
                }
            }
        }
        // Counted barrier: LDS-only drain. hb[p^1] writes complete (lgkmcnt(0))
        // before any wave proceeds; global loads/stores keep flying.
        asm volatile("s_waitcnt lgkmcnt(0)\n\ts_barrier" ::: "memory");

        #pragma unroll
        for (int i = 0; i < 4; ++i) Hp[i] += DH;
    }
    // final stores (Hp points at row TT)
    #pragma unroll
    for (int q = 0; q < 4; ++q)
        #pragma unroll
        for (int i = 0; i < 4; ++i) Hp[i][q * 16 - 512] = acc[q][i];
}

// ---------------- Pass 3: O = H(65536x512) @ wO(512x128) ----------------
__global__ __launch_bounds__(256, 1) void k_O(const float* __restrict__ H,
                                              const float* __restrict__ wO,
                                              float* __restrict__ O) {
    __shared__ __align__(16) f16 Bt[DOUT][520];
    __shared__ __align__(16) f16 At[64][136];
    const int tid = threadIdx.x;
    const int wv = tid >> 6, ln = tid & 63, l15 = ln & 15, g = ln >> 4;
    const int m0 = (int)blockIdx.x * 64;

    for (int u = 0; u < 64; ++u) {
        int flat = u * 256 + tid;
        int r = flat >> 5;
        int c4 = (flat & 31) << 2;
        const float4 w4 = *(const float4*)(wO + (size_t)r * DOUT + c4);
        Bt[c4 + 0][r] = (f16)w4.x;
        Bt[c4 + 1][r] = (f16)w4.y;
        Bt[c4 + 2][r] = (f16)w4.z;
        Bt[c4 + 3][r] = (f16)w4.w;
    }

    f32x4 acc[8];
    #pragma unroll
    for (int nt = 0; nt < 8; ++nt) acc[nt] = (f32x4){0.f, 0.f, 0.f, 0.f};

    for (int kc = 0; kc < 4; ++kc) {
        __syncthreads();
        {
            int r = tid >> 2;
            int cb = (tid & 3) << 5;
            #pragma unroll
            for (int u = 0; u < 8; ++u) {
                int c = cb + u * 4;
                const float4 x4 = *(const float4*)(H + (size_t)(m0 + r) * DH + kc * 128 + c);
                f16x4 h4;
                h4[0] = (f16)x4.x; h4[1] = (f16)x4.y; h4[2] = (f16)x4.z; h4[3] = (f16)x4.w;
                *(f16x4*)((char*)&At[r][0] + c * 2) = h4;
            }
        }
        __syncthreads();
        #pragma unroll
        for (int c = 0; c < 8; ++c) {
            const int k0 = c * 16 + g * 4;
            const f16x4 a = *(const f16x4*)((const char*)&At[wv * 16 + l15][0] + k0 * 2);
            #pragma unroll
            for (int nt = 0; nt < 8; ++nt) {
                const f16x4 b =
                    *(const f16x4*)((const char*)&Bt[nt * 16 + l15][0] + (kc * 128 + k0) * 2);
                acc[nt] = MFMA16(a, b, acc[nt]);
            }
        }
    }
    #pragma unroll
    for (int i = 0; i < 4; ++i) {
        const int m = m0 + wv * 16 + g * 4 + i;
        #pragma unroll
        for (int nt = 0; nt < 8; ++nt) O[(size_t)m * DOUT + nt * 16 + l15] = acc[nt][i];
    }
}

extern "C" void kernel_launch(void* const* d_in, const int* in_sizes, int n_in,
                              void* d_out, int out_size, void* d_ws, size_t ws_size,
                              hipStream_t stream) {
    const float* X  = (const float*)d_in[0];
    const float* h0 = (const float*)d_in[1];
    const float* wI = (const float*)d_in[2];
    const float* wR = (const float*)d_in[3];
    const float* wO = (const float*)d_in[4];
    float* O = (float*)d_out;
    float* H = O + O_ELEMS;  // H region; also holds xI (fp32) before in-place scan

    k_xI<<<1024, 256, 0, stream>>>(X, wI, H);   // xI -> H region
    k_scan<<<4, 512, 0, stream>>>(wR, h0, H);   // in-place: xI -> H
    k_O<<<1024, 256, 0, stream>>>(H, wO, O);    // O = H @ wO
}

// Round 9
// 3289.483 us; speedup vs baseline: 1.4858x; 1.2331x over previous
//
#include <hip/hip_runtime.h>
#include <cstdint>
#include <cstddef>

typedef _Float16 f16;
typedef _Float16 f16x4 __attribute__((ext_vector_type(4)));
typedef _Float16 f16x8 __attribute__((ext_vector_type(8)));
typedef float f32x4 __attribute__((ext_vector_type(4)));

#define MFMA16(a, b, c) __builtin_amdgcn_mfma_f32_16x16x16f16((a), (b), (c), 0, 0, 0)
#define MFMA32(a, b, c) __builtin_amdgcn_mfma_f32_16x16x32_f16((a), (b), (c), 0, 0, 0)

constexpr int TT = 1024, DIN = 128, DH = 512, DOUT = 128;
constexpr size_t O_ELEMS = (size_t)64 * 1024 * 128;

// Row swizzle for [row][1KB] LDS tiles (R8-proven). b128 operand reads are at the
// 8-pass floor; the ~4 "conflict" counts per b128 read are a counter artifact.
__device__ __forceinline__ uint32_t SW(uint32_t r) {
    return ((r & 7u) << 4) ^ ((r & 8u) << 2);
}

// ---------------- Pass 1: xI = X(65536x128) @ wI(128x512) -> H region (fp32) ----------------
__global__ __launch_bounds__(256, 1) void k_xI(const float* __restrict__ X,
                                               const float* __restrict__ wI,
                                               float* __restrict__ xI) {
    __shared__ __align__(16) f16 Bt[DH][136];
    __shared__ __align__(16) f16 At[64][136];
    const int tid = threadIdx.x;
    const int wv = tid >> 6, ln = tid & 63, l15 = ln & 15, g = ln >> 4;
    const int m0 = (int)blockIdx.x * 64;

    for (int u = 0; u < 64; ++u) {
        int flat = u * 256 + tid;
        int r = flat >> 7;
        int c4 = (flat & 127) << 2;
        const float4 w4 = *(const float4*)(wI + (size_t)r * DH + c4);
        Bt[c4 + 0][r] = (f16)w4.x;
        Bt[c4 + 1][r] = (f16)w4.y;
        Bt[c4 + 2][r] = (f16)w4.z;
        Bt[c4 + 3][r] = (f16)w4.w;
    }
    {
        int r = tid >> 2;
        int cb = (tid & 3) << 5;
        #pragma unroll
        for (int u = 0; u < 8; ++u) {
            int c = cb + u * 4;
            const float4 x4 = *(const float4*)(X + (size_t)(m0 + r) * DIN + c);
            f16x4 h4;
            h4[0] = (f16)x4.x; h4[1] = (f16)x4.y; h4[2] = (f16)x4.z; h4[3] = (f16)x4.w;
            *(f16x4*)((char*)&At[r][0] + c * 2) = h4;
        }
    }
    __syncthreads();

    f32x4 acc[4][8];
    #pragma unroll
    for (int mt = 0; mt < 4; ++mt)
        #pragma unroll
        for (int nt = 0; nt < 8; ++nt) acc[mt][nt] = (f32x4){0.f, 0.f, 0.f, 0.f};

    #pragma unroll
    for (int c = 0; c < 8; ++c) {
        const int k0 = c * 16 + g * 4;
        f16x4 a[4];
        #pragma unroll
        for (int mt = 0; mt < 4; ++mt)
            a[mt] = *(const f16x4*)((const char*)&At[mt * 16 + l15][0] + k0 * 2);
        #pragma unroll
        for (int nt = 0; nt < 8; ++nt) {
            const int n = wv * 128 + nt * 16 + l15;
            const f16x4 b = *(const f16x4*)((const char*)&Bt[n][0] + k0 * 2);
            #pragma unroll
            for (int mt = 0; mt < 4; ++mt) acc[mt][nt] = MFMA16(a[mt], b, acc[mt][nt]);
        }
    }
    #pragma unroll
    for (int mt = 0; mt < 4; ++mt) {
        #pragma unroll
        for (int i = 0; i < 4; ++i) {
            const int m = m0 + mt * 16 + g * 4 + i;
            float* orow = xI + (size_t)m * DH + wv * 128 + l15;
            #pragma unroll
            for (int nt = 0; nt < 8; ++nt) orow[nt * 16] = acc[mt][nt][i];
        }
    }
}

// ---------------- Pass 2: recurrent scan -------------------------------------------------
// 4 blocks x 16 batches, 8 waves/block (2/SIMD). x32 MFMA, K=32 chunks.
// Per wave: 64 j = 4 tiles; 3 in registers, 1 in LDS (hb 32KB + 8x16KB = 160KB).
// NEW vs R8: 2-deep software pipeline on BOTH LDS operand streams (a from hb,
// b from the wave's LDS B-tile) so the ~120cy ds_read latency hides under 2
// chunks (~155cy) of MFMA issue; H stores moved into the epilogue (fly across
// the counted barrier into the next step's MFMA phase).
__global__ __launch_bounds__(512, 2) void k_scan(const float* __restrict__ wR,
                                                 const float* __restrict__ h0,
                                                 float* __restrict__ Hb) {
    __shared__ __align__(16) char sm[163840];
    const int tid = threadIdx.x;
    const int wv = tid >> 6, ln = tid & 63, l15 = ln & 15, g = ln >> 4;
    const int bb = (int)blockIdx.x * 16;

    // ---- stage wR: 3 register j-tiles per wave; frag[i] = wR[c*32+g*8+i][j] ----
    f16x8 Brf[3][16];
    #pragma unroll
    for (int q = 0; q < 3; ++q) {
        const int j = wv * 64 + q * 16 + l15;
        #pragma unroll
        for (int c = 0; c < 16; ++c) {
            const float* pw = wR + (size_t)(c * 32 + g * 8) * DH + j;
            f16x8 v;
            #pragma unroll
            for (int i = 0; i < 8; ++i) v[i] = (f16)pw[(size_t)i * DH];
            Brf[q][c] = v;
        }
    }
    // ---- stage wR: 1 LDS j-tile per wave (j = t8*64 + 48 + j16), cooperative ----
    for (int idx = tid; idx < 8 * 16 * 512; idx += 512) {
        const int j16 = idx & 15;
        const int k = (idx >> 4) & 511;
        const int t8 = idx >> 13;
        const float v = wR[(size_t)k * DH + t8 * 64 + 48 + j16];
        *(f16*)(sm + 32768 + t8 * 16384 + j16 * 1024 +
                (((uint32_t)(k * 2)) ^ SW((uint32_t)j16))) = (f16)v;
    }
    // ---- h0 broadcast into hb[0] ----
    {
        const int j = tid;  // 0..511
        const f16 v = (f16)h0[j];
        #pragma unroll
        for (uint32_t r = 0; r < 16; ++r)
            *(f16*)(sm + r * 1024 + (((uint32_t)(j * 2)) ^ SW(r))) = v;
    }

    const int jbase = wv * 64 + l15;
    float* Hp[4];
    #pragma unroll
    for (int i = 0; i < 4; ++i)
        Hp[i] = Hb + (size_t)(bb + g * 4 + i) * TT * DH + jbase;

    // k-chunk offset: off = (c<<6) ^ pre
    const uint32_t pre =
        (((uint32_t)(g ^ (l15 & 7))) << 4) ^ (((uint32_t)(l15 & 8)) << 2);
    const uint32_t lanebase = (uint32_t)l15 * 1024;
    const uint32_t jb2 = (uint32_t)jbase * 2;

    // prologue: xI(0) into xr
    float xr[4][4];
    #pragma unroll
    for (int q = 0; q < 4; ++q)
        #pragma unroll
        for (int i = 0; i < 4; ++i) xr[q][i] = Hp[i][q * 16];

    f32x4 acc[4];

    __syncthreads();

    #pragma unroll 1
    for (int t = 0; t < TT; ++t) {
        const uint32_t p = (uint32_t)(t & 1);
        // acc <- xI(t)  (MFMA C-in carries the input projection)
        #pragma unroll
        for (int q = 0; q < 4; ++q)
            #pragma unroll
            for (int i = 0; i < 4; ++i) acc[q][i] = xr[q][i];
        // prefetch xI(t+1) into the now-free xr regs; lands during the MFMA phase
        if (t + 1 < TT) {
            #pragma unroll
            for (int q = 0; q < 4; ++q)
                #pragma unroll
                for (int i = 0; i < 4; ++i) xr[q][i] = Hp[i][q * 16 + 512];
        }

        // h @ wR : 16 K=32 chunks; 3 register B-tiles + 1 LDS B-tile.
        // 2-deep rotating prefetch on both LDS streams.
        {
            const char* hbp = sm + p * 16384 + lanebase;
            const char* blp = sm + 32768 + (uint32_t)wv * 16384 + lanebase;
            f16x8 a0 = *(const f16x8*)(hbp + (0u ^ pre));
            f16x8 b0 = *(const f16x8*)(blp + (0u ^ pre));
            f16x8 a1 = *(const f16x8*)(hbp + (64u ^ pre));
            f16x8 b1 = *(const f16x8*)(blp + (64u ^ pre));
            #pragma unroll
            for (int c = 0; c < 16; ++c) {
                f16x8 an, bn;
                if (c < 14) {
                    const uint32_t off2 = (((uint32_t)(c + 2)) << 6) ^ pre;
                    an = *(const f16x8*)(hbp + off2);
                    bn = *(const f16x8*)(blp + off2);
                }
                acc[0] = MFMA32(a0, Brf[0][c], acc[0]);
                acc[1] = MFMA32(a0, Brf[1][c], acc[1]);
                acc[2] = MFMA32(a0, Brf[2][c], acc[2]);
                acc[3] = MFMA32(a0, b0, acc[3]);
                a0 = a1; b0 = b1;
                if (c < 14) { a1 = an; b1 = bn; }
            }
        }

        // epilogue: th = tanh(acc); H(t) <- fp32 th (global, flies across the
        // barrier); hb[p^1] <- f16 th (LDS, covered by the counted barrier)
        {
            char* hw = sm + (p ^ 1u) * 16384;
            #pragma unroll
            for (int q = 0; q < 4; ++q) {
                #pragma unroll
                for (int i = 0; i < 4; ++i) {
                    const uint32_t r = (uint32_t)g * 4 + (uint32_t)i;
                    const float x = acc[q][i];
                    const float e = __builtin_amdgcn_exp2f(x * 2.8853900817779268f);
                    const float th = 1.0f - 2.0f * __builtin_amdgcn_rcpf(e + 1.0f);
                    Hp[i][q * 16] = th;
                    *(f16*)(hw + r * 1024 + ((jb2 + (uint32_t)q * 32) ^ SW(r))) = (f16)th;
                }
            }
        }
        // Counted barrier: LDS-only drain; global loads/stores keep flying.
        asm volatile("s_waitcnt lgkmcnt(0)\n\ts_barrier" ::: "memory");

        #pragma unroll
        for (int i = 0; i < 4; ++i) Hp[i] += DH;
    }
}

// ---------------- Pass 3: O = H(65536x512) @ wO(512x128) ----------------
__global__ __launch_bounds__(256, 1) void k_O(const float* __restrict__ H,
                                              const float* __restrict__ wO,
                                              float* __restrict__ O) {
    __shared__ __align__(16) f16 Bt[DOUT][520];
    __shared__ __align__(16) f16 At[64][136];
    const int tid = threadIdx.x;
    const int wv = tid >> 6, ln = tid & 63, l15 = ln & 15, g = ln >> 4;
    const int m0 = (int)blockIdx.x * 64;

    for (int u = 0; u < 64; ++u) {
        int flat = u * 256 + tid;
        int r = flat >> 5;
        int c4 = (flat & 31) << 2;
        const float4 w4 = *(const float4*)(wO + (size_t)r * DOUT + c4);
        Bt[c4 + 0][r] = (f16)w4.x;
        Bt[c4 + 1][r] = (f16)w4.y;
        Bt[c4 + 2][r] = (f16)w4.z;
        Bt[c4 + 3][r] = (f16)w4.w;
    }

    f32x4 acc[8];
    #pragma unroll
    for (int nt = 0; nt < 8; ++nt) acc[nt] = (f32x4){0.f, 0.f, 0.f, 0.f};

    for (int kc = 0; kc < 4; ++kc) {
        __syncthreads();
        {
            int r = tid >> 2;
            int cb = (tid & 3) << 5;
            #pragma unroll
            for (int u = 0; u < 8; ++u) {
                int c = cb + u * 4;
                const float4 x4 = *(const float4*)(H + (size_t)(m0 + r) * DH + kc * 128 + c);
                f16x4 h4;
                h4[0] = (f16)x4.x; h4[1] = (f16)x4.y; h4[2] = (f16)x4.z; h4[3] = (f16)x4.w;
                *(f16x4*)((char*)&At[r][0] + c * 2) = h4;
            }
        }
        __syncthreads();
        #pragma unroll
        for (int c = 0; c < 8; ++c) {
            const int k0 = c * 16 + g * 4;
            const f16x4 a = *(const f16x4*)((const char*)&At[wv * 16 + l15][0] + k0 * 2);
            #pragma unroll
            for (int nt = 0; nt < 8; ++nt) {
                const f16x4 b =
                    *(const f16x4*)((const char*)&Bt[nt * 16 + l15][0] + (kc * 128 + k0) * 2);
                acc[nt] = MFMA16(a, b, acc[nt]);
            }
        }
    }
    #pragma unroll
    for (int i = 0; i < 4; ++i) {
        const int m = m0 + wv * 16 + g * 4 + i;
        #pragma unroll
        for (int nt = 0; nt < 8; ++nt) O[(size_t)m * DOUT + nt * 16 + l15] = acc[nt][i];
    }
}

extern "C" void kernel_launch(void* const* d_in, const int* in_sizes, int n_in,
                              void* d_out, int out_size, void* d_ws, size_t ws_size,
                              hipStream_t stream) {
    const float* X  = (const float*)d_in[0];
    const float* h0 = (const float*)d_in[1];
    const float* wI = (const float*)d_in[2];
    const float* wR = (const float*)d_in[3];
    const float* wO = (const float*)d_in[4];
    float* O = (float*)d_out;
    float* H = O + O_ELEMS;  // H region; also holds xI (fp32) before in-place scan

    k_xI<<<1024, 256, 0, stream>>>(X, wI, H);   // xI -> H region
    k_scan<<<4, 512, 0, stream>>>(wR, h0, H);   // in-place: xI -> H
    k_O<<<1024, 256, 0, stream>>>(H, wO, O);    // O = H @ wO
}

// Round 10
// 2191.373 us; speedup vs baseline: 2.2304x; 1.5011x over previous
//
#include <hip/hip_runtime.h>
#include <cstdint>
#include <cstddef>

typedef _Float16 f16;
typedef _Float16 f16x4 __attribute__((ext_vector_type(4)));
typedef _Float16 f16x8 __attribute__((ext_vector_type(8)));
typedef float f32x4 __attribute__((ext_vector_type(4)));

#define MFMA16(a, b, c) __builtin_amdgcn_mfma_f32_16x16x16f16((a), (b), (c), 0, 0, 0)
#define MFMA32(a, b, c) __builtin_amdgcn_mfma_f32_16x16x32_f16((a), (b), (c), 0, 0, 0)

constexpr int TT = 1024, DIN = 128, DH = 512, DOUT = 128;
constexpr size_t O_ELEMS = (size_t)64 * 1024 * 128;

// Row swizzle for [row][1KB] LDS tiles (R8/R9-proven).
__device__ __forceinline__ uint32_t SW(uint32_t r) {
    return ((r & 7u) << 4) ^ ((r & 8u) << 2);
}

// ---------------- Pass 1: xI = X(65536x128) @ wI(128x512) -> H region (fp32) ----------------
__global__ __launch_bounds__(256, 1) void k_xI(const float* __restrict__ X,
                                               const float* __restrict__ wI,
                                               float* __restrict__ xI) {
    __shared__ __align__(16) f16 Bt[DH][136];
    __shared__ __align__(16) f16 At[64][136];
    const int tid = threadIdx.x;
    const int wv = tid >> 6, ln = tid & 63, l15 = ln & 15, g = ln >> 4;
    const int m0 = (int)blockIdx.x * 64;

    for (int u = 0; u < 64; ++u) {
        int flat = u * 256 + tid;
        int r = flat >> 7;
        int c4 = (flat & 127) << 2;
        const float4 w4 = *(const float4*)(wI + (size_t)r * DH + c4);
        Bt[c4 + 0][r] = (f16)w4.x;
        Bt[c4 + 1][r] = (f16)w4.y;
        Bt[c4 + 2][r] = (f16)w4.z;
        Bt[c4 + 3][r] = (f16)w4.w;
    }
    {
        int r = tid >> 2;
        int cb = (tid & 3) << 5;
        #pragma unroll
        for (int u = 0; u < 8; ++u) {
            int c = cb + u * 4;
            const float4 x4 = *(const float4*)(X + (size_t)(m0 + r) * DIN + c);
            f16x4 h4;
            h4[0] = (f16)x4.x; h4[1] = (f16)x4.y; h4[2] = (f16)x4.z; h4[3] = (f16)x4.w;
            *(f16x4*)((char*)&At[r][0] + c * 2) = h4;
        }
    }
    __syncthreads();

    f32x4 acc[4][8];
    #pragma unroll
    for (int mt = 0; mt < 4; ++mt)
        #pragma unroll
        for (int nt = 0; nt < 8; ++nt) acc[mt][nt] = (f32x4){0.f, 0.f, 0.f, 0.f};

    #pragma unroll
    for (int c = 0; c < 8; ++c) {
        const int k0 = c * 16 + g * 4;
        f16x4 a[4];
        #pragma unroll
        for (int mt = 0; mt < 4; ++mt)
            a[mt] = *(const f16x4*)((const char*)&At[mt * 16 + l15][0] + k0 * 2);
        #pragma unroll
        for (int nt = 0; nt < 8; ++nt) {
            const int n = wv * 128 + nt * 16 + l15;
            const f16x4 b = *(const f16x4*)((const char*)&Bt[n][0] + k0 * 2);
            #pragma unroll
            for (int mt = 0; mt < 4; ++mt) acc[mt][nt] = MFMA16(a[mt], b, acc[mt][nt]);
        }
    }
    #pragma unroll
    for (int mt = 0; mt < 4; ++mt) {
        #pragma unroll
        for (int i = 0; i < 4; ++i) {
            const int m = m0 + mt * 16 + g * 4 + i;
            float* orow = xI + (size_t)m * DH + wv * 128 + l15;
            #pragma unroll
            for (int nt = 0; nt < 8; ++nt) orow[nt * 16] = acc[mt][nt][i];
        }
    }
}

// ---------------- Pass 2: recurrent scan -------------------------------------------------
// 4 blocks x 16 batches, 8 waves/block (2/SIMD). x32 MFMA, K=32 chunks.
// TRANSPOSED MFMA vs R9: D = wR^T (A, from Brf regs / LDS tile) * h^T (B, from hb).
// A/B fragment layouts are mirrored, so all staging and read addresses are
// UNCHANGED; only the accumulator orientation flips: thread (l15,g) now owns
// batch l15, j = wv*64 + q*16 + g*4 + i  ->  contiguous-in-j per thread:
//   * H stores / xI loads become 4x dwordx4 (was 16x dword)
//   * hb writes become 4x ds_write_b64 f16x4 (was 16x ds_write_b16)
// Plus: 3-deep static ring on both LDS streams (no rotation movs).
// LDS map unchanged: [0,16K) hb[0] | [16K,32K) hb[1] | [32K,160K) 8 B j-tiles.
__global__ __launch_bounds__(512, 2) void k_scan(const float* __restrict__ wR,
                                                 const float* __restrict__ h0,
                                                 float* __restrict__ Hb) {
    __shared__ __align__(16) char sm[163840];
    const int tid = threadIdx.x;
    const int wv = tid >> 6, ln = tid & 63, l15 = ln & 15, g = ln >> 4;
    const int bb = (int)blockIdx.x * 16;

    // ---- stage wR: 3 register j-tiles per wave; frag[e] = wR[c*32+g*8+e][j] ----
    // (used as the A-operand: A[row=l15 -> j][k=32c+8g+e] = wR^T[j][k])
    f16x8 Brf[3][16];
    #pragma unroll
    for (int q = 0; q < 3; ++q) {
        const int j = wv * 64 + q * 16 + l15;
        #pragma unroll
        for (int c = 0; c < 16; ++c) {
            const float* pw = wR + (size_t)(c * 32 + g * 8) * DH + j;
            f16x8 v;
            #pragma unroll
            for (int i = 0; i < 8; ++i) v[i] = (f16)pw[(size_t)i * DH];
            Brf[q][c] = v;
        }
    }
    // ---- stage wR: 1 LDS j-tile per wave (j = t8*64 + 48 + j16), cooperative ----
    for (int idx = tid; idx < 8 * 16 * 512; idx += 512) {
        const int j16 = idx & 15;
        const int k = (idx >> 4) & 511;
        const int t8 = idx >> 13;
        const float v = wR[(size_t)k * DH + t8 * 64 + 48 + j16];
        *(f16*)(sm + 32768 + t8 * 16384 + j16 * 1024 +
                (((uint32_t)(k * 2)) ^ SW((uint32_t)j16))) = (f16)v;
    }
    // ---- h0 broadcast into hb[0] ----
    {
        const int j = tid;  // 0..511
        const f16 v = (f16)h0[j];
        #pragma unroll
        for (uint32_t r = 0; r < 16; ++r)
            *(f16*)(sm + r * 1024 + (((uint32_t)(j * 2)) ^ SW(r))) = v;
    }

    // this thread's batch row and j-base
    float* Hp = Hb + (size_t)(bb + l15) * TT * DH + wv * 64 + g * 4;

    // k-chunk read offset: off = (c<<6) ^ pre (same algebra as R9, both streams)
    const uint32_t pre =
        (((uint32_t)(g ^ (l15 & 7))) << 4) ^ (((uint32_t)(l15 & 8)) << 2);
    const uint32_t lanebase = (uint32_t)l15 * 1024;
    const uint32_t wbase = (uint32_t)(wv * 128 + g * 8);  // j*2 base for hb writes
    const uint32_t swl = SW((uint32_t)l15);

    // prologue: xI(0) into xr (vector loads)
    f32x4 xr[4];
    #pragma unroll
    for (int q = 0; q < 4; ++q) xr[q] = *(const f32x4*)(Hp + q * 16);

    f32x4 acc[4];

    __syncthreads();

    #pragma unroll 1
    for (int t = 0; t < TT; ++t) {
        const uint32_t p = (uint32_t)(t & 1);
        // acc <- xI(t)  (MFMA C-in carries the input projection)
        #pragma unroll
        for (int q = 0; q < 4; ++q) acc[q] = xr[q];
        // prefetch xI(t+1); loads stay in flight across the counted barrier
        if (t + 1 < TT) {
            #pragma unroll
            for (int q = 0; q < 4; ++q) xr[q] = *(const f32x4*)(Hp + 512 + q * 16);
        }

        // wR^T @ h^T : 16 K=32 chunks; 3-deep static ring on both LDS streams
        {
            const char* hbp = sm + p * 16384 + lanebase;
            const char* blp = sm + 32768 + (uint32_t)wv * 16384 + lanebase;
            f16x8 ab[3], b3[3];
            #pragma unroll
            for (int s = 0; s < 3; ++s) {
                const uint32_t off = (((uint32_t)s) << 6) ^ pre;
                ab[s] = *(const f16x8*)(hbp + off);
                b3[s] = *(const f16x8*)(blp + off);
            }
            #pragma unroll
            for (int c = 0; c < 16; ++c) {
                const int s = c % 3;  // static after full unroll
                const f16x8 a = ab[s];
                const f16x8 bt = b3[s];
                if (c < 13) {
                    const uint32_t off3 = (((uint32_t)(c + 3)) << 6) ^ pre;
                    ab[s] = *(const f16x8*)(hbp + off3);
                    b3[s] = *(const f16x8*)(blp + off3);
                }
                acc[0] = MFMA32(Brf[0][c], a, acc[0]);
                acc[1] = MFMA32(Brf[1][c], a, acc[1]);
                acc[2] = MFMA32(Brf[2][c], a, acc[2]);
                acc[3] = MFMA32(bt, a, acc[3]);
            }
        }

        // epilogue: th = tanh(acc); H(t) <- float4 th; hb[p^1] <- packed f16x4
        {
            char* hw = sm + (p ^ 1u) * 16384 + lanebase;
            #pragma unroll
            for (int q = 0; q < 4; ++q) {
                f32x4 th4;
                f16x4 hv;
                #pragma unroll
                for (int i = 0; i < 4; ++i) {
                    const float x = acc[q][i];
                    const float e = __builtin_amdgcn_exp2f(x * 2.8853900817779268f);
                    const float th = 1.0f - 2.0f * __builtin_amdgcn_rcpf(e + 1.0f);
                    th4[i] = th;
                    hv[i] = (f16)th;
                }
                *(f32x4*)(Hp + q * 16) = th4;  // H(t), coalesced dwordx4
                *(f16x4*)(hw + ((wbase + (uint32_t)q * 32) ^ swl)) = hv;  // b64 write
            }
        }
        // Counted barrier: LDS-only drain; global loads/stores keep flying.
        asm volatile("s_waitcnt lgkmcnt(0)\n\ts_barrier" ::: "memory");

        Hp += DH;
    }
}

// ---------------- Pass 3: O = H(65536x512) @ wO(512x128) ----------------
__global__ __launch_bounds__(256, 1) void k_O(const float* __restrict__ H,
                                              const float* __restrict__ wO,
                                              float* __restrict__ O) {
    __shared__ __align__(16) f16 Bt[DOUT][520];
    __shared__ __align__(16) f16 At[64][136];
    const int tid = threadIdx.x;
    const int wv = tid >> 6, ln = tid & 63, l15 = ln & 15, g = ln >> 4;
    const int m0 = (int)blockIdx.x * 64;

    for (int u = 0; u < 64; ++u) {
        int flat = u * 256 + tid;
        int r = flat >> 5;
        int c4 = (flat & 31) << 2;
        const float4 w4 = *(const float4*)(wO + (size_t)r * DOUT + c4);
        Bt[c4 + 0][r] = (f16)w4.x;
        Bt[c4 + 1][r] = (f16)w4.y;
        Bt[c4 + 2][r] = (f16)w4.z;
        Bt[c4 + 3][r] = (f16)w4.w;
    }

    f32x4 acc[8];
    #pragma unroll
    for (int nt = 0; nt < 8; ++nt) acc[nt] = (f32x4){0.f, 0.f, 0.f, 0.f};

    for (int kc = 0; kc < 4; ++kc) {
        __syncthreads();
        {
            int r = tid >> 2;
            int cb = (tid & 3) << 5;
            #pragma unroll
            for (int u = 0; u < 8; ++u) {
                int c = cb + u * 4;
                const float4 x4 = *(const float4*)(H + (size_t)(m0 + r) * DH + kc * 128 + c);
                f16x4 h4;
                h4[0] = (f16)x4.x; h4[1] = (f16)x4.y; h4[2] = (f16)x4.z; h4[3] = (f16)x4.w;
                *(f16x4*)((char*)&At[r][0] + c * 2) = h4;
            }
        }
        __syncthreads();
        #pragma unroll
        for (int c = 0; c < 8; ++c) {
            const int k0 = c * 16 + g * 4;
            const f16x4 a = *(const f16x4*)((const char*)&At[wv * 16 + l15][0] + k0 * 2);
            #pragma unroll
            for (int nt = 0; nt < 8; ++nt) {
                const f16x4 b =
                    *(const f16x4*)((const char*)&Bt[nt * 16 + l15][0] + (kc * 128 + k0) * 2);
                acc[nt] = MFMA16(a, b, acc[nt]);
            }
        }
    }
    #pragma unroll
    for (int i = 0; i < 4; ++i) {
        const int m = m0 + wv * 16 + g * 4 + i;
        #pragma unroll
        for (int nt = 0; nt < 8; ++nt) O[(size_t)m * DOUT + nt * 16 + l15] = acc[nt][i];
    }
}

extern "C" void kernel_launch(void* const* d_in, const int* in_sizes, int n_in,
                              void* d_out, int out_size, void* d_ws, size_t ws_size,
                              hipStream_t stream) {
    const float* X  = (const float*)d_in[0];
    const float* h0 = (const float*)d_in[1];
    const float* wI = (const float*)d_in[2];
    const float* wR = (const float*)d_in[3];
    const float* wO = (const float*)d_in[4];
    float* O = (float*)d_out;
    float* H = O + O_ELEMS;  // H region; also holds xI (fp32) before in-place scan

    k_xI<<<1024, 256, 0, stream>>>(X, wI, H);   // xI -> H region
    k_scan<<<4, 512, 0, stream>>>(wR, h0, H);   // in-place: xI -> H
    k_O<<<1024, 256, 0, stream>>>(H, wO, O);    // O = H @ wO
}